// Round 21
// baseline (428.627 us; speedup 1.0000x reference)
//
#include <hip/hip_runtime.h>
#include <math.h>

#define EMB 64
static constexpr float INV_SQRT_DK = 0.17677669529663687f; // 1/sqrt(32)

#define NBK 128           // KG bucket blocks (long dense runs)
#define NBU 48            // UI bucket blocks
#define P3_PROJ 1024      // proj-role blocks in K1
#define P2PROJ 1024       // proj-role blocks in P2
#define PSHIFT 9          // 512-node partitions
#define PRANGE 512
#define CAPK 14336
#define CAPU 14336

typedef unsigned uint2v __attribute__((ext_vector_type(2)));
typedef float floatx2 __attribute__((ext_vector_type(2)));

__device__ inline unsigned short f2bf(float f) {
    union { float f; unsigned u; } v; v.f = f;
    unsigned r = v.u + 0x7FFF + ((v.u >> 16) & 1);   // round-to-nearest-even
    return (unsigned short)(r >> 16);
}
__device__ inline float bfhi(unsigned w) {           // high 16 bits as bf16
    union { float f; unsigned u; } v; v.u = w & 0xFFFF0000u; return v.f;
}
__device__ inline float bflo(unsigned w) {           // low 16 bits as bf16
    union { float f; unsigned u; } v; v.u = w << 16; return v.f;
}
__device__ inline float bf2f(unsigned short b) {
    union { float f; unsigned u; } v; v.u = ((unsigned)b) << 16; return v.f;
}
__device__ inline floatx2 fp8lo(unsigned v) {    // bytes 0,1 (e4m3)
    return __builtin_amdgcn_cvt_pk_f32_fp8((int)v, false);
}
__device__ inline floatx2 fp8hi(unsigned v) {    // bytes 2,3
    return __builtin_amdgcn_cvt_pk_f32_fp8((int)v, true);
}

// ---- proj core: wave handles 4 rows; lane=(rsub<<4)|sub handles dims 4sub..4sub+3.
// emits 12B/4dims: [bf16 pj0|pj1][bf16 pj2|pj3][4x fp8 val]; optionally vl (fp8 row).
template <bool FROM_BF16>
__device__ inline void proj_rows12(const void* __restrict__ ein, const float4* __restrict__ Wl4,
                                   unsigned char* __restrict__ pk12, unsigned* __restrict__ vl,
                                   int n, int g0, int nG, int lane) {
    int rsub = lane >> 4;
    int sub  = lane & 15;
    for (int g = g0; g * 4 < n; g += nG) {
        int r = g * 4 + rsub;
        float x0 = 0.f, x1 = 0.f, x2 = 0.f, x3 = 0.f;
        if (r < n) {
            if (FROM_BF16) {
                ushort4 xv = *(const ushort4*)((const unsigned short*)ein + (size_t)r * EMB + sub * 4);
                x0 = bf2f(xv.x); x1 = bf2f(xv.y); x2 = bf2f(xv.z); x3 = bf2f(xv.w);
            } else {
                float4 xv = *(const float4*)((const float*)ein + (size_t)r * EMB + sub * 4);
                x0 = xv.x; x1 = xv.y; x2 = xv.z; x3 = xv.w;
            }
        }
        float a0 = 0.f, a1 = 0.f, a2 = 0.f, a3 = 0.f;
#pragma unroll
        for (int kb = 0; kb < 16; ++kb) {
            int src = (rsub << 4) | kb;
            float e0 = __shfl(x0, src, 64);
            float e1 = __shfl(x1, src, 64);
            float e2 = __shfl(x2, src, 64);
            float e3 = __shfl(x3, src, 64);
            float4 w0 = Wl4[(kb * 4 + 0) * 16 + sub];
            float4 w1 = Wl4[(kb * 4 + 1) * 16 + sub];
            float4 w2 = Wl4[(kb * 4 + 2) * 16 + sub];
            float4 w3 = Wl4[(kb * 4 + 3) * 16 + sub];
            a0 = fmaf(e0, w0.x, a0); a1 = fmaf(e0, w0.y, a1); a2 = fmaf(e0, w0.z, a2); a3 = fmaf(e0, w0.w, a3);
            a0 = fmaf(e1, w1.x, a0); a1 = fmaf(e1, w1.y, a1); a2 = fmaf(e1, w1.z, a2); a3 = fmaf(e1, w1.w, a3);
            a0 = fmaf(e2, w2.x, a0); a1 = fmaf(e2, w2.y, a1); a2 = fmaf(e2, w2.z, a2); a3 = fmaf(e2, w2.w, a3);
            a0 = fmaf(e3, w3.x, a0); a1 = fmaf(e3, w3.y, a1); a2 = fmaf(e3, w3.z, a2); a3 = fmaf(e3, w3.w, a3);
        }
        if (r < n) {
            unsigned u0 = ((unsigned)f2bf(a1) << 16) | f2bf(a0);
            unsigned u1 = ((unsigned)f2bf(a3) << 16) | f2bf(a2);
            int p8 = __builtin_amdgcn_cvt_pk_fp8_f32(x0, x1, 0, false);
            p8 = __builtin_amdgcn_cvt_pk_fp8_f32(x2, x3, p8, true);
            uint3* dst = (uint3*)(pk12 + (size_t)r * 192 + sub * 12);
            *dst = make_uint3(u0, u1, (unsigned)p8);
            if (vl) vl[(size_t)r * 16 + sub] = (unsigned)p8;
        }
    }
}

// ---- K1: fixed-capacity partition bucketing MERGED with hop-1 proj (512 threads) ----
// Bucket stores are PLAIN (not nontemporal): L2 write-combines the dense runs.
__global__ void __launch_bounds__(512) k1_bucket_proj(
        const int* __restrict__ head, const int* __restrict__ tail,
        const int* __restrict__ etype, int E,
        int* __restrict__ pdK, unsigned* __restrict__ bktK,
        const int* __restrict__ iu, const int* __restrict__ ii,
        const float* __restrict__ w, int EI,
        int* __restrict__ pdU, uint2v* __restrict__ bktU,
        const float* __restrict__ e_in, const float* __restrict__ W,
        unsigned char* __restrict__ pk12, unsigned* __restrict__ vl,
        int n_ent, int nPartH, int nPartU) {
    __shared__ float sh[64 * 64];
    int b = blockIdx.x;
    int t = threadIdx.x;
    if (b >= NBK + NBU) {
        for (int i = t; i < 64 * 64; i += 512) sh[i] = W[i];
        __syncthreads();
        int lane = t & 63;
        int g0 = (b - (NBK + NBU)) * 8 + (t >> 6);
        proj_rows12<false>(e_in, (const float4*)sh, pk12, vl, n_ent, g0, P3_PROJ * 8, lane);
        return;
    }
    int* lc = (int*)sh;
    if (t < 256) lc[t] = 0;
    __syncthreads();
    if (b < NBK) {
        int chunk = (E + NBK - 1) / NBK;
        int lo = b * chunk, hi = min(lo + chunk, E);
        for (int e = lo + t; e < hi; e += 512)
            atomicAdd(&lc[__builtin_nontemporal_load(&head[e]) >> PSHIFT], 1);
        __syncthreads();
        if (t < nPartH)
            lc[t] = t * CAPK + atomicAdd(&pdK[t], lc[t]);
        __syncthreads();
        for (int e = lo + t; e < hi; e += 512) {
            int h = __builtin_nontemporal_load(&head[e]);
            int tl = __builtin_nontemporal_load(&tail[e]);
            int ty = __builtin_nontemporal_load(&etype[e]);
            int pos = atomicAdd(&lc[h >> PSHIFT], 1);
            bktK[pos] = ((unsigned)(h & (PRANGE - 1)) << 21) | (unsigned)(tl | ((ty - 1) << 17));
        }
    } else {
        int bb = b - NBK;
        int chunk = (EI + NBU - 1) / NBU;
        int lo = bb * chunk, hi = min(lo + chunk, EI);
        for (int e = lo + t; e < hi; e += 512)
            atomicAdd(&lc[__builtin_nontemporal_load(&iu[e]) >> PSHIFT], 1);
        __syncthreads();
        if (t < nPartU)
            lc[t] = t * CAPU + atomicAdd(&pdU[t], lc[t]);
        __syncthreads();
        for (int e = lo + t; e < hi; e += 512) {
            int u = __builtin_nontemporal_load(&iu[e]);
            int it = __builtin_nontemporal_load(&ii[e]);
            float wv = __builtin_nontemporal_load(&w[e]);
            int pos = atomicAdd(&lc[u >> PSHIFT], 1);
            unsigned wq = (unsigned)(wv * 32767.f + 0.5f);
            uint2v r; r.x = (unsigned)it | (wq << 17); r.y = (unsigned)u;
            bktU[pos] = r;
        }
    }
}

// ---- K2: per-partition LDS counting sort -> node-sorted col[] + off[] ----
__global__ void __launch_bounds__(512) k2_sort(
        const unsigned* __restrict__ bktK, const int* __restrict__ pdK,
        int* __restrict__ off_h, int* __restrict__ col_h, int n_ent, int nPartH, int E,
        const uint2v* __restrict__ bktU, const int* __restrict__ pdU,
        int* __restrict__ off_u, unsigned* __restrict__ col_ui, int n_usr, int nPartU, int EI) {
    __shared__ int hist[PRANGE];
    __shared__ int wsum[8];
    int t = threadIdx.x;
    int lane = t & 63, wv = t >> 6;
    int b = blockIdx.x;
    bool isU = b >= nPartH;
    int p = isU ? b - nPartH : b;
    const int* pd = isU ? pdU : pdK;
    int cnt = min(pd[p], isU ? CAPU : CAPK);
    int contrib = (t < p) ? pd[t] : 0;
#pragma unroll
    for (int m = 1; m <= 32; m <<= 1) contrib += __shfl_xor(contrib, m, 64);
    if (lane == 0) wsum[wv] = contrib;
    hist[t] = 0;
    __syncthreads();
    int Sp = wsum[0] + wsum[1] + wsum[2] + wsum[3] + wsum[4] + wsum[5] + wsum[6] + wsum[7];
    if (!isU) {
        const unsigned* bk = bktK + (size_t)p * CAPK;
        for (int i = t; i < cnt; i += 512)
            atomicAdd(&hist[__builtin_nontemporal_load(&bk[i]) >> 21], 1);
    } else {
        const uint2v* bu = bktU + (size_t)p * CAPU;
        int plo0 = p << PSHIFT;
        for (int i = t; i < cnt; i += 512) {
            uint2v r = __builtin_nontemporal_load(&bu[i]);
            atomicAdd(&hist[(int)r.y - plo0], 1);
        }
    }
    __syncthreads();
    int v0 = 0, v1 = 0, ps = 0, incl = 0;
    if (t < 256) { v0 = hist[2 * t]; v1 = hist[2 * t + 1]; ps = v0 + v1; incl = ps; }
#pragma unroll
    for (int d = 1; d <= 32; d <<= 1) { int x = __shfl_up(incl, d, 64); if (lane >= d) incl += x; }
    __syncthreads();
    if (t < 256 && lane == 63) wsum[wv] = incl;
    __syncthreads();
    int plo = p << PSHIFT;
    if (t < 256) {
        int woff = 0;
        for (int i = 0; i < wv; ++i) woff += wsum[i];
        int ex = incl - ps + woff;
        int nmax = isU ? n_usr : n_ent;
        int* off = isU ? off_u : off_h;
        if (plo + 2 * t < nmax)     off[plo + 2 * t]     = Sp + ex;
        if (plo + 2 * t + 1 < nmax) off[plo + 2 * t + 1] = Sp + ex + v0;
        hist[2 * t] = Sp + ex;
        hist[2 * t + 1] = Sp + ex + v0;
    }
    if (b == 0 && t == 0) off_h[n_ent] = E;
    if (b == nPartH && t == 0) off_u[n_usr] = EI;
    __syncthreads();
    if (!isU) {
        const unsigned* bk = bktK + (size_t)p * CAPK;
        for (int i = t; i < cnt; i += 512) {
            unsigned r = __builtin_nontemporal_load(&bk[i]);
            int pos = atomicAdd(&hist[r >> 21], 1);
            col_h[pos] = (int)(r & 0x1FFFFFu);
        }
    } else {
        const uint2v* bu = bktU + (size_t)p * CAPU;
        for (int i = t; i < cnt; i += 512) {
            uint2v r = __builtin_nontemporal_load(&bu[i]);
            int pos = atomicAdd(&hist[(int)r.y - plo], 1);
            col_ui[pos] = r.x;
        }
    }
}

// per-edge KG compute: score from bf16 pj, values from fp8; accumulates num/den
#define KG_EDGE12(W, RL, INVD) {                                            \
        float prod = q0 * RL.x * bflo(W.x);                                 \
        prod = fmaf(q1 * RL.y, bfhi(W.x), prod);                            \
        prod = fmaf(q2 * RL.z, bflo(W.y), prod);                            \
        prod = fmaf(q3 * RL.w, bfhi(W.y), prod);                            \
        prod += __shfl_xor(prod, 1, 64);                                    \
        prod += __shfl_xor(prod, 2, 64);                                    \
        prod += __shfl_xor(prod, 4, 64);                                    \
        float ex = __expf(prod * INV_SQRT_DK);                              \
        if (INVD) ex = 0.f;                                                 \
        den += ex;                                                          \
        floatx2 vlo = fp8lo(W.z), vhi = fp8hi(W.z);                         \
        num0 = fmaf(ex * RL.x, vlo.x, num0);                                \
        num1 = fmaf(ex * RL.y, vlo.y, num1);                                \
        num2 = fmaf(ex * RL.z, vhi.x, num2);                                \
        num3 = fmaf(ex * RL.w, vhi.y, num3); }

// ------- fused agg, 4 dims/lane 4 edges/wave, KG edge loop unrolled x4 (16 in flight) -------
template <bool HOP1>
__global__ void __launch_bounds__(256) agg_fused_kernel(
        const unsigned char* __restrict__ pk12,
        const unsigned* __restrict__ vl,          // HOP1 UI value table (fp8)
        unsigned short* __restrict__ enorm_out,   // HOP1 out
        const float* __restrict__ rel_emb,
        const int* __restrict__ off_h, const int* __restrict__ col_h,
        const int* __restrict__ off_u, const unsigned* __restrict__ col_ui,
        const float* __restrict__ e_base, float* __restrict__ e_res, int n_ent,
        const float* __restrict__ u_base, float* __restrict__ u_res,
        int n_usr, int kgBlocks, int totalBlocks) {
    __shared__ float4 relS4[16 * 16];
    int bid = blockIdx.x;
    size_t lo = (size_t)bid * kgBlocks / totalBlocks;
    size_t hi = (size_t)(bid + 1) * kgBlocks / totalBlocks;
    int lane = threadIdx.x & 63;
    int wslot = threadIdx.x >> 6;
    int slot = lane >> 4;
    int sub  = lane & 15;
    int dd   = sub * 4;

    if (hi > lo) {
        // ---------------- KG entity block ----------------
        for (int i = threadIdx.x; i < 16 * 16; i += blockDim.x)
            relS4[i] = ((const float4*)rel_emb)[i];
        __syncthreads();
        int wid = (int)lo * 4 + wslot;
        if (wid >= n_ent) return;
        int s = off_h[wid], e = off_h[wid + 1];
        uint3 qw = *(const uint3*)(pk12 + (size_t)wid * 192 + sub * 12);
        float q0 = bflo(qw.x), q1 = bfhi(qw.x), q2 = bflo(qw.y), q3 = bfhi(qw.y);
        float num0 = 0.f, num1 = 0.f, num2 = 0.f, num3 = 0.f, den = 0.f;
        int j = s;
        for (; j + 15 < e; j += 16) {         // 4 groups of 4 edges, all gathers in flight
            int pA = col_h[j + slot];
            int pB = col_h[j + 4 + slot];
            int pC = col_h[j + 8 + slot];
            int pD = col_h[j + 12 + slot];
            uint3 wA = *(const uint3*)(pk12 + (size_t)(pA & 131071) * 192 + sub * 12);
            uint3 wB = *(const uint3*)(pk12 + (size_t)(pB & 131071) * 192 + sub * 12);
            uint3 wC = *(const uint3*)(pk12 + (size_t)(pC & 131071) * 192 + sub * 12);
            uint3 wD = *(const uint3*)(pk12 + (size_t)(pD & 131071) * 192 + sub * 12);
            float4 rlA = relS4[(pA >> 17) * 16 + sub];
            float4 rlB = relS4[(pB >> 17) * 16 + sub];
            float4 rlC = relS4[(pC >> 17) * 16 + sub];
            float4 rlD = relS4[(pD >> 17) * 16 + sub];
            KG_EDGE12(wA, rlA, false);
            KG_EDGE12(wB, rlB, false);
            KG_EDGE12(wC, rlC, false);
            KG_EDGE12(wD, rlD, false);
        }
        for (; j + 7 < e; j += 8) {           // 2 groups
            int pA = col_h[j + slot];
            int pB = col_h[j + 4 + slot];
            uint3 wA = *(const uint3*)(pk12 + (size_t)(pA & 131071) * 192 + sub * 12);
            uint3 wB = *(const uint3*)(pk12 + (size_t)(pB & 131071) * 192 + sub * 12);
            float4 rlA = relS4[(pA >> 17) * 16 + sub];
            float4 rlB = relS4[(pB >> 17) * 16 + sub];
            KG_EDGE12(wA, rlA, false);
            KG_EDGE12(wB, rlB, false);
        }
        for (; j < e; j += 4) {               // remainder (may have dummy lanes)
            int jj = j + slot;
            bool invd = jj >= e;
            if (invd) jj = e - 1;
            int p = col_h[jj];
            uint3 w = *(const uint3*)(pk12 + (size_t)(p & 131071) * 192 + sub * 12);
            float4 rl = relS4[(p >> 17) * 16 + sub];
            KG_EDGE12(w, rl, invd);
        }
        den  += __shfl_xor(den, 16, 64);  den  += __shfl_xor(den, 32, 64);
        num0 += __shfl_xor(num0, 16, 64); num0 += __shfl_xor(num0, 32, 64);
        num1 += __shfl_xor(num1, 16, 64); num1 += __shfl_xor(num1, 32, 64);
        num2 += __shfl_xor(num2, 16, 64); num2 += __shfl_xor(num2, 32, 64);
        num3 += __shfl_xor(num3, 16, 64); num3 += __shfl_xor(num3, 32, 64);
        float dinv = (e > s) ? 1.f / den : 0.f;
        float v0 = num0 * dinv, v1 = num1 * dinv, v2 = num2 * dinv, v3 = num3 * dinv;
        float ss = fmaf(v0, v0, fmaf(v1, v1, fmaf(v2, v2, v3 * v3)));
        ss += __shfl_xor(ss, 1, 64);
        ss += __shfl_xor(ss, 2, 64);
        ss += __shfl_xor(ss, 4, 64);
        ss += __shfl_xor(ss, 8, 64);
        float rn = 1.f / fmaxf(sqrtf(ss), 1e-12f);
        float o0 = v0 * rn, o1 = v1 * rn, o2 = v2 * rn, o3 = v3 * rn;
        if (slot == 0) {
            size_t ix = (size_t)wid * EMB + dd;
            if (HOP1) {
                ushort4 nb; nb.x = f2bf(o0); nb.y = f2bf(o1); nb.z = f2bf(o2); nb.w = f2bf(o3);
                *(ushort4*)&enorm_out[ix] = nb;
                float4 bv = *(const float4*)&e_base[ix];
                *(float4*)&e_res[ix] = make_float4(bv.x + o0, bv.y + o1, bv.z + o2, bv.w + o3);
            } else {
                float4 rv = *(const float4*)&e_res[ix];
                *(float4*)&e_res[ix] = make_float4(rv.x + o0, rv.y + o1, rv.z + o2, rv.w + o3);
            }
        }
    } else if (HOP1) {
        // ---------------- UI user block (fp8 value table), hop-1 only ----------------
        int wid = (bid - (int)lo) * 4 + wslot;
        if (wid >= n_usr) return;
        int s = off_u[wid], e = off_u[wid + 1];
        float a0 = 0.f, a1 = 0.f, a2 = 0.f, a3 = 0.f;
        int j = s;
        for (; j + 7 < e; j += 8) {
            unsigned cA = col_ui[j + slot];
            unsigned cB = col_ui[j + 4 + slot];
            unsigned vA = vl[(size_t)(cA & 131071u) * 16 + sub];
            unsigned vB = vl[(size_t)(cB & 131071u) * 16 + sub];
            float wvA = (cA >> 17) * (1.f / 32767.f);
            float wvB = (cB >> 17) * (1.f / 32767.f);
            floatx2 lA = fp8lo(vA), hA = fp8hi(vA);
            a0 = fmaf(wvA, lA.x, a0); a1 = fmaf(wvA, lA.y, a1);
            a2 = fmaf(wvA, hA.x, a2); a3 = fmaf(wvA, hA.y, a3);
            floatx2 lB = fp8lo(vB), hB = fp8hi(vB);
            a0 = fmaf(wvB, lB.x, a0); a1 = fmaf(wvB, lB.y, a1);
            a2 = fmaf(wvB, hB.x, a2); a3 = fmaf(wvB, hB.y, a3);
        }
        for (; j < e; j += 4) {
            int jj = j + slot;
            bool invd = jj >= e;
            if (invd) jj = e - 1;
            unsigned c = col_ui[jj];
            float wv = invd ? 0.f : (c >> 17) * (1.f / 32767.f);
            unsigned vv = vl[(size_t)(c & 131071u) * 16 + sub];
            floatx2 vlo = fp8lo(vv), vhi = fp8hi(vv);
            a0 = fmaf(wv, vlo.x, a0);
            a1 = fmaf(wv, vlo.y, a1);
            a2 = fmaf(wv, vhi.x, a2);
            a3 = fmaf(wv, vhi.y, a3);
        }
        a0 += __shfl_xor(a0, 16, 64); a0 += __shfl_xor(a0, 32, 64);
        a1 += __shfl_xor(a1, 16, 64); a1 += __shfl_xor(a1, 32, 64);
        a2 += __shfl_xor(a2, 16, 64); a2 += __shfl_xor(a2, 32, 64);
        a3 += __shfl_xor(a3, 16, 64); a3 += __shfl_xor(a3, 32, 64);
        float ss = fmaf(a0, a0, fmaf(a1, a1, fmaf(a2, a2, a3 * a3)));
        ss += __shfl_xor(ss, 1, 64);
        ss += __shfl_xor(ss, 2, 64);
        ss += __shfl_xor(ss, 4, 64);
        ss += __shfl_xor(ss, 8, 64);
        float rn = 1.f / fmaxf(sqrtf(ss), 1e-12f);
        float o0 = a0 * rn, o1 = a1 * rn, o2 = a2 * rn, o3 = a3 * rn;
        if (slot == 0) {
            size_t ix = (size_t)wid * EMB + dd;
            float4 bv = *(const float4*)&u_base[ix];
            *(float4*)&u_res[ix] = make_float4(bv.x + o0, bv.y + o1, bv.z + o2, bv.w + o3);
        }
    }
}

// ---- P2: hop-2 proj (enorm -> pk12_2, 512 thr) MERGED with hop-2 UI agg (enorm values) ----
__global__ void __launch_bounds__(512) p2_proj_ui(
        const unsigned short* __restrict__ enorm, const float* __restrict__ W,
        unsigned char* __restrict__ pk12_2, int n_ent,
        const int* __restrict__ off_u, const unsigned* __restrict__ col_ui,
        float* __restrict__ u_res, int n_usr) {
    __shared__ float sh[64 * 64];
    int b = blockIdx.x;
    int t = threadIdx.x;
    int lane = t & 63;
    if (b < P2PROJ) {
        for (int i = t; i < 64 * 64; i += 512) sh[i] = W[i];
        __syncthreads();
        int g0 = b * 8 + (t >> 6);
        proj_rows12<true>(enorm, (const float4*)sh, pk12_2, nullptr, n_ent, g0, P2PROJ * 8, lane);
        return;
    }
    int wid = (b - P2PROJ) * 8 + (t >> 6);
    if (wid >= n_usr) return;
    int slot = lane >> 4;
    int sub  = lane & 15;
    int dd   = sub * 4;
    int s = off_u[wid], e = off_u[wid + 1];
    float a0 = 0.f, a1 = 0.f, a2 = 0.f, a3 = 0.f;
    int j = s;
    for (; j + 7 < e; j += 8) {
        unsigned cA = col_ui[j + slot];
        unsigned cB = col_ui[j + 4 + slot];
        ushort4 vA = *(const ushort4*)&enorm[(size_t)(cA & 131071u) * EMB + dd];
        ushort4 vB = *(const ushort4*)&enorm[(size_t)(cB & 131071u) * EMB + dd];
        float wvA = (cA >> 17) * (1.f / 32767.f);
        float wvB = (cB >> 17) * (1.f / 32767.f);
        a0 = fmaf(wvA, bf2f(vA.x), a0); a1 = fmaf(wvA, bf2f(vA.y), a1);
        a2 = fmaf(wvA, bf2f(vA.z), a2); a3 = fmaf(wvA, bf2f(vA.w), a3);
        a0 = fmaf(wvB, bf2f(vB.x), a0); a1 = fmaf(wvB, bf2f(vB.y), a1);
        a2 = fmaf(wvB, bf2f(vB.z), a2); a3 = fmaf(wvB, bf2f(vB.w), a3);
    }
    for (; j < e; j += 4) {
        int jj = j + slot;
        bool invd = jj >= e;
        if (invd) jj = e - 1;
        unsigned c = col_ui[jj];
        float wv = invd ? 0.f : (c >> 17) * (1.f / 32767.f);
        ushort4 v = *(const ushort4*)&enorm[(size_t)(c & 131071u) * EMB + dd];
        a0 = fmaf(wv, bf2f(v.x), a0);
        a1 = fmaf(wv, bf2f(v.y), a1);
        a2 = fmaf(wv, bf2f(v.z), a2);
        a3 = fmaf(wv, bf2f(v.w), a3);
    }
    a0 += __shfl_xor(a0, 16, 64); a0 += __shfl_xor(a0, 32, 64);
    a1 += __shfl_xor(a1, 16, 64); a1 += __shfl_xor(a1, 32, 64);
    a2 += __shfl_xor(a2, 16, 64); a2 += __shfl_xor(a2, 32, 64);
    a3 += __shfl_xor(a3, 16, 64); a3 += __shfl_xor(a3, 32, 64);
    float ss = fmaf(a0, a0, fmaf(a1, a1, fmaf(a2, a2, a3 * a3)));
    ss += __shfl_xor(ss, 1, 64);
    ss += __shfl_xor(ss, 2, 64);
    ss += __shfl_xor(ss, 4, 64);
    ss += __shfl_xor(ss, 8, 64);
    float rn = 1.f / fmaxf(sqrtf(ss), 1e-12f);
    if (slot == 0) {
        size_t ix = (size_t)wid * EMB + dd;
        float4 rv = *(const float4*)&u_res[ix];
        *(float4*)&u_res[ix] = make_float4(rv.x + a0 * rn, rv.y + a1 * rn,
                                           rv.z + a2 * rn, rv.w + a3 * rn);
    }
}

extern "C" void kernel_launch(void* const* d_in, const int* in_sizes, int n_in,
                              void* d_out, int out_size, void* d_ws, size_t ws_size,
                              hipStream_t stream) {
    const float* user_emb   = (const float*)d_in[0];
    const float* entity_emb = (const float*)d_in[1];
    const int*   edge_index = (const int*)d_in[2];   // [2, E]
    const int*   edge_type  = (const int*)d_in[3];   // [E]
    const int*   inter_edge = (const int*)d_in[4];   // [2, EI]
    const float* inter_w    = (const float*)d_in[5]; // [EI]
    const float* W_Q        = (const float*)d_in[6]; // [64,64]
    const float* rel_emb    = (const float*)d_in[7]; // [16,64]

    const int E     = in_sizes[3];
    const int EI    = in_sizes[5];
    const int n_ent = in_sizes[1] / EMB;
    const int n_usr = in_sizes[0] / EMB;

    const int* head = edge_index;
    const int* tail = edge_index + E;
    const int* iu   = inter_edge;
    const int* ii   = inter_edge + EI;

    const int nPartH = (n_ent + PRANGE - 1) >> PSHIFT;   // 196
    const int nPartU = (n_usr + PRANGE - 1) >> PSHIFT;   // 98

    // ---- workspace layout ----
    char* ws = (char*)d_ws;
    unsigned char* pk12   = (unsigned char*)ws;  ws += (size_t)n_ent * 192;   // hop-1 KG table
    unsigned*      vl     = (unsigned*)ws;       ws += (size_t)n_ent * 64;    // hop-1 UI fp8
    unsigned char* pk12_2 = (unsigned char*)ws;  ws += (size_t)n_ent * 192;   // hop-2 KG table
    unsigned short* enorm = (unsigned short*)ws; ws += (size_t)n_ent * EMB * 2;
    int*      col_h  = (int*)ws;               ws += (size_t)E * 4;
    unsigned* col_ui = (unsigned*)ws;          ws += (size_t)EI * 4;
    int*   off_h = (int*)ws;                   ws += (size_t)(n_ent + 1) * 4;
    int*   off_u = (int*)ws;                   ws += (size_t)(n_usr + 1) * 4;
    int*   pdK   = (int*)ws;                   ws += 256 * 4;
    int*   pdU   = (int*)ws;                   ws += 256 * 4;
    // buckets overlay pk12_2 + enorm (dead until agg1/p2 write them; k2 consumes first)
    unsigned* bktK = (unsigned*)pk12_2;                          // ~11.2 MB
    uint2v*   bktU = (uint2v*)(bktK + (size_t)nPartH * CAPK);    // ~11.2 MB

    float* e_res = (float*)d_out;
    float* u_res = e_res + (size_t)n_ent * EMB;

    // ---- CSR build: fixed-capacity bucket sort ----
    hipMemsetAsync(pdK, 0, 512 * 4, stream);
    k1_bucket_proj<<<NBK + NBU + P3_PROJ, 512, 0, stream>>>(
        head, tail, edge_type, E, pdK, bktK,
        iu, ii, inter_w, EI, pdU, bktU,
        entity_emb, W_Q, pk12, vl, n_ent, nPartH, nPartU);
    k2_sort<<<nPartH + nPartU, 512, 0, stream>>>(
        bktK, pdK, off_h, col_h, n_ent, nPartH, E,
        bktU, pdU, off_u, col_ui, n_usr, nPartU, EI);

    const int kgBlocks = (n_ent + 3) / 4;
    const int uiBlocks = (n_usr + 3) / 4;
    const int totalBlocks = kgBlocks + uiBlocks;
    const int uiBlocks8 = (n_usr + 7) / 8;

    // ---- hop 1 (KG+UI; emits enorm) ----
    agg_fused_kernel<true><<<totalBlocks, 256, 0, stream>>>(
        pk12, vl, enorm, rel_emb, off_h, col_h, off_u, col_ui,
        entity_emb, e_res, n_ent, user_emb, u_res, n_usr, kgBlocks, totalBlocks);

    // ---- hop-2 proj (enorm->pk12_2)  ||  hop-2 UI agg (enorm values) ----
    p2_proj_ui<<<P2PROJ + uiBlocks8, 512, 0, stream>>>(
        enorm, W_Q, pk12_2, n_ent, off_u, col_ui, u_res, n_usr);

    // ---- hop 2 KG-only ----
    agg_fused_kernel<false><<<kgBlocks, 256, 0, stream>>>(
        pk12_2, nullptr, nullptr, rel_emb, off_h, col_h, nullptr, nullptr,
        nullptr, e_res, n_ent, nullptr, nullptr, 0, kgBlocks, kgBlocks);
}

// Round 22
// 404.651 us; speedup vs baseline: 1.0593x; 1.0593x over previous
//
#include <hip/hip_runtime.h>
#include <math.h>

#define EMB 64
static constexpr float INV_SQRT_DK = 0.17677669529663687f; // 1/sqrt(32)

#define NBK 128           // KG bucket blocks (long dense runs)
#define NBU 48            // UI bucket blocks
#define P3_PROJ 1024      // proj-role blocks in K1
#define P2PROJ 1024       // proj-role blocks in P2
#define PSHIFT 9          // 512-node partitions
#define PRANGE 512
#define CAPK 14336
#define CAPU 14336

typedef unsigned uint2v __attribute__((ext_vector_type(2)));
typedef float floatx2 __attribute__((ext_vector_type(2)));

__device__ inline unsigned short f2bf(float f) {
    union { float f; unsigned u; } v; v.f = f;
    unsigned r = v.u + 0x7FFF + ((v.u >> 16) & 1);   // round-to-nearest-even
    return (unsigned short)(r >> 16);
}
__device__ inline float bfhi(unsigned w) {           // high 16 bits as bf16
    union { float f; unsigned u; } v; v.u = w & 0xFFFF0000u; return v.f;
}
__device__ inline float bflo(unsigned w) {           // low 16 bits as bf16
    union { float f; unsigned u; } v; v.u = w << 16; return v.f;
}
__device__ inline float bf2f(unsigned short b) {
    union { float f; unsigned u; } v; v.u = ((unsigned)b) << 16; return v.f;
}
__device__ inline floatx2 fp8lo(unsigned v) {    // bytes 0,1 (e4m3)
    return __builtin_amdgcn_cvt_pk_f32_fp8((int)v, false);
}
__device__ inline floatx2 fp8hi(unsigned v) {    // bytes 2,3
    return __builtin_amdgcn_cvt_pk_f32_fp8((int)v, true);
}

// ---- proj core: wave handles 4 rows; lane=(rsub<<4)|sub handles dims 4sub..4sub+3.
// emits 12B/4dims: [bf16 pj0|pj1][bf16 pj2|pj3][4x fp8 val]; optionally vl (fp8 row).
template <bool FROM_BF16>
__device__ inline void proj_rows12(const void* __restrict__ ein, const float4* __restrict__ Wl4,
                                   unsigned char* __restrict__ pk12, unsigned* __restrict__ vl,
                                   int n, int g0, int nG, int lane) {
    int rsub = lane >> 4;
    int sub  = lane & 15;
    for (int g = g0; g * 4 < n; g += nG) {
        int r = g * 4 + rsub;
        float x0 = 0.f, x1 = 0.f, x2 = 0.f, x3 = 0.f;
        if (r < n) {
            if (FROM_BF16) {
                ushort4 xv = *(const ushort4*)((const unsigned short*)ein + (size_t)r * EMB + sub * 4);
                x0 = bf2f(xv.x); x1 = bf2f(xv.y); x2 = bf2f(xv.z); x3 = bf2f(xv.w);
            } else {
                float4 xv = *(const float4*)((const float*)ein + (size_t)r * EMB + sub * 4);
                x0 = xv.x; x1 = xv.y; x2 = xv.z; x3 = xv.w;
            }
        }
        float a0 = 0.f, a1 = 0.f, a2 = 0.f, a3 = 0.f;
#pragma unroll
        for (int kb = 0; kb < 16; ++kb) {
            int src = (rsub << 4) | kb;
            float e0 = __shfl(x0, src, 64);
            float e1 = __shfl(x1, src, 64);
            float e2 = __shfl(x2, src, 64);
            float e3 = __shfl(x3, src, 64);
            float4 w0 = Wl4[(kb * 4 + 0) * 16 + sub];
            float4 w1 = Wl4[(kb * 4 + 1) * 16 + sub];
            float4 w2 = Wl4[(kb * 4 + 2) * 16 + sub];
            float4 w3 = Wl4[(kb * 4 + 3) * 16 + sub];
            a0 = fmaf(e0, w0.x, a0); a1 = fmaf(e0, w0.y, a1); a2 = fmaf(e0, w0.z, a2); a3 = fmaf(e0, w0.w, a3);
            a0 = fmaf(e1, w1.x, a0); a1 = fmaf(e1, w1.y, a1); a2 = fmaf(e1, w1.z, a2); a3 = fmaf(e1, w1.w, a3);
            a0 = fmaf(e2, w2.x, a0); a1 = fmaf(e2, w2.y, a1); a2 = fmaf(e2, w2.z, a2); a3 = fmaf(e2, w2.w, a3);
            a0 = fmaf(e3, w3.x, a0); a1 = fmaf(e3, w3.y, a1); a2 = fmaf(e3, w3.z, a2); a3 = fmaf(e3, w3.w, a3);
        }
        if (r < n) {
            unsigned u0 = ((unsigned)f2bf(a1) << 16) | f2bf(a0);
            unsigned u1 = ((unsigned)f2bf(a3) << 16) | f2bf(a2);
            int p8 = __builtin_amdgcn_cvt_pk_fp8_f32(x0, x1, 0, false);
            p8 = __builtin_amdgcn_cvt_pk_fp8_f32(x2, x3, p8, true);
            uint3* dst = (uint3*)(pk12 + (size_t)r * 192 + sub * 12);
            *dst = make_uint3(u0, u1, (unsigned)p8);
            if (vl) vl[(size_t)r * 16 + sub] = (unsigned)p8;
        }
    }
}

// ---- K1: fixed-capacity partition bucketing MERGED with hop-1 proj (512 threads) ----
// Bucket stores are PLAIN (not nontemporal): L2 write-combines the dense runs.
__global__ void __launch_bounds__(512) k1_bucket_proj(
        const int* __restrict__ head, const int* __restrict__ tail,
        const int* __restrict__ etype, int E,
        int* __restrict__ pdK, unsigned* __restrict__ bktK,
        const int* __restrict__ iu, const int* __restrict__ ii,
        const float* __restrict__ w, int EI,
        int* __restrict__ pdU, uint2v* __restrict__ bktU,
        const float* __restrict__ e_in, const float* __restrict__ W,
        unsigned char* __restrict__ pk12, unsigned* __restrict__ vl,
        int n_ent, int nPartH, int nPartU) {
    __shared__ float sh[64 * 64];
    int b = blockIdx.x;
    int t = threadIdx.x;
    if (b >= NBK + NBU) {
        for (int i = t; i < 64 * 64; i += 512) sh[i] = W[i];
        __syncthreads();
        int lane = t & 63;
        int g0 = (b - (NBK + NBU)) * 8 + (t >> 6);
        proj_rows12<false>(e_in, (const float4*)sh, pk12, vl, n_ent, g0, P3_PROJ * 8, lane);
        return;
    }
    int* lc = (int*)sh;
    if (t < 256) lc[t] = 0;
    __syncthreads();
    if (b < NBK) {
        int chunk = (E + NBK - 1) / NBK;
        int lo = b * chunk, hi = min(lo + chunk, E);
        for (int e = lo + t; e < hi; e += 512)
            atomicAdd(&lc[__builtin_nontemporal_load(&head[e]) >> PSHIFT], 1);
        __syncthreads();
        if (t < nPartH)
            lc[t] = t * CAPK + atomicAdd(&pdK[t], lc[t]);
        __syncthreads();
        for (int e = lo + t; e < hi; e += 512) {
            int h = __builtin_nontemporal_load(&head[e]);
            int tl = __builtin_nontemporal_load(&tail[e]);
            int ty = __builtin_nontemporal_load(&etype[e]);
            int pos = atomicAdd(&lc[h >> PSHIFT], 1);
            bktK[pos] = ((unsigned)(h & (PRANGE - 1)) << 21) | (unsigned)(tl | ((ty - 1) << 17));
        }
    } else {
        int bb = b - NBK;
        int chunk = (EI + NBU - 1) / NBU;
        int lo = bb * chunk, hi = min(lo + chunk, EI);
        for (int e = lo + t; e < hi; e += 512)
            atomicAdd(&lc[__builtin_nontemporal_load(&iu[e]) >> PSHIFT], 1);
        __syncthreads();
        if (t < nPartU)
            lc[t] = t * CAPU + atomicAdd(&pdU[t], lc[t]);
        __syncthreads();
        for (int e = lo + t; e < hi; e += 512) {
            int u = __builtin_nontemporal_load(&iu[e]);
            int it = __builtin_nontemporal_load(&ii[e]);
            float wv = __builtin_nontemporal_load(&w[e]);
            int pos = atomicAdd(&lc[u >> PSHIFT], 1);
            unsigned wq = (unsigned)(wv * 32767.f + 0.5f);
            uint2v r; r.x = (unsigned)it | (wq << 17); r.y = (unsigned)u;
            bktU[pos] = r;
        }
    }
}

// ---- K2: per-partition LDS counting sort -> node-sorted col[] + off[] ----
__global__ void __launch_bounds__(512) k2_sort(
        const unsigned* __restrict__ bktK, const int* __restrict__ pdK,
        int* __restrict__ off_h, int* __restrict__ col_h, int n_ent, int nPartH, int E,
        const uint2v* __restrict__ bktU, const int* __restrict__ pdU,
        int* __restrict__ off_u, unsigned* __restrict__ col_ui, int n_usr, int nPartU, int EI) {
    __shared__ int hist[PRANGE];
    __shared__ int wsum[8];
    int t = threadIdx.x;
    int lane = t & 63, wv = t >> 6;
    int b = blockIdx.x;
    bool isU = b >= nPartH;
    int p = isU ? b - nPartH : b;
    const int* pd = isU ? pdU : pdK;
    int cnt = min(pd[p], isU ? CAPU : CAPK);
    int contrib = (t < p) ? pd[t] : 0;
#pragma unroll
    for (int m = 1; m <= 32; m <<= 1) contrib += __shfl_xor(contrib, m, 64);
    if (lane == 0) wsum[wv] = contrib;
    hist[t] = 0;
    __syncthreads();
    int Sp = wsum[0] + wsum[1] + wsum[2] + wsum[3] + wsum[4] + wsum[5] + wsum[6] + wsum[7];
    if (!isU) {
        const unsigned* bk = bktK + (size_t)p * CAPK;
        for (int i = t; i < cnt; i += 512)
            atomicAdd(&hist[__builtin_nontemporal_load(&bk[i]) >> 21], 1);
    } else {
        const uint2v* bu = bktU + (size_t)p * CAPU;
        int plo0 = p << PSHIFT;
        for (int i = t; i < cnt; i += 512) {
            uint2v r = __builtin_nontemporal_load(&bu[i]);
            atomicAdd(&hist[(int)r.y - plo0], 1);
        }
    }
    __syncthreads();
    int v0 = 0, v1 = 0, ps = 0, incl = 0;
    if (t < 256) { v0 = hist[2 * t]; v1 = hist[2 * t + 1]; ps = v0 + v1; incl = ps; }
#pragma unroll
    for (int d = 1; d <= 32; d <<= 1) { int x = __shfl_up(incl, d, 64); if (lane >= d) incl += x; }
    __syncthreads();
    if (t < 256 && lane == 63) wsum[wv] = incl;
    __syncthreads();
    int plo = p << PSHIFT;
    if (t < 256) {
        int woff = 0;
        for (int i = 0; i < wv; ++i) woff += wsum[i];
        int ex = incl - ps + woff;
        int nmax = isU ? n_usr : n_ent;
        int* off = isU ? off_u : off_h;
        if (plo + 2 * t < nmax)     off[plo + 2 * t]     = Sp + ex;
        if (plo + 2 * t + 1 < nmax) off[plo + 2 * t + 1] = Sp + ex + v0;
        hist[2 * t] = Sp + ex;
        hist[2 * t + 1] = Sp + ex + v0;
    }
    if (b == 0 && t == 0) off_h[n_ent] = E;
    if (b == nPartH && t == 0) off_u[n_usr] = EI;
    __syncthreads();
    if (!isU) {
        const unsigned* bk = bktK + (size_t)p * CAPK;
        for (int i = t; i < cnt; i += 512) {
            unsigned r = __builtin_nontemporal_load(&bk[i]);
            int pos = atomicAdd(&hist[r >> 21], 1);
            col_h[pos] = (int)(r & 0x1FFFFFu);
        }
    } else {
        const uint2v* bu = bktU + (size_t)p * CAPU;
        for (int i = t; i < cnt; i += 512) {
            uint2v r = __builtin_nontemporal_load(&bu[i]);
            int pos = atomicAdd(&hist[(int)r.y - plo], 1);
            col_ui[pos] = r.x;
        }
    }
}

// per-edge KG compute: score from bf16 pj, values from fp8; accumulates num/den
#define KG_EDGE12(W, RL, INVD) {                                            \
        float prod = q0 * RL.x * bflo(W.x);                                 \
        prod = fmaf(q1 * RL.y, bfhi(W.x), prod);                            \
        prod = fmaf(q2 * RL.z, bflo(W.y), prod);                            \
        prod = fmaf(q3 * RL.w, bfhi(W.y), prod);                            \
        prod += __shfl_xor(prod, 1, 64);                                    \
        prod += __shfl_xor(prod, 2, 64);                                    \
        prod += __shfl_xor(prod, 4, 64);                                    \
        float ex = __expf(prod * INV_SQRT_DK);                              \
        if (INVD) ex = 0.f;                                                 \
        den += ex;                                                          \
        floatx2 vlo = fp8lo(W.z), vhi = fp8hi(W.z);                         \
        num0 = fmaf(ex * RL.x, vlo.x, num0);                                \
        num1 = fmaf(ex * RL.y, vlo.y, num1);                                \
        num2 = fmaf(ex * RL.z, vhi.x, num2);                                \
        num3 = fmaf(ex * RL.w, vhi.y, num3); }

// ------- fused agg, 4 dims/lane 4 edges/wave, KG edge loop unrolled x4 (16 in flight) -------
template <bool HOP1>
__global__ void __launch_bounds__(256) agg_fused_kernel(
        const unsigned char* __restrict__ pk12,
        const unsigned* __restrict__ vl,          // HOP1 UI value table (fp8)
        unsigned short* __restrict__ enorm_out,   // HOP1 out
        const float* __restrict__ rel_emb,
        const int* __restrict__ off_h, const int* __restrict__ col_h,
        const int* __restrict__ off_u, const unsigned* __restrict__ col_ui,
        const float* __restrict__ e_base, float* __restrict__ e_res, int n_ent,
        const float* __restrict__ u_base, float* __restrict__ u_res,
        int n_usr, int kgBlocks, int totalBlocks) {
    __shared__ float4 relS4[16 * 16];
    int bid = blockIdx.x;
    size_t lo = (size_t)bid * kgBlocks / totalBlocks;
    size_t hi = (size_t)(bid + 1) * kgBlocks / totalBlocks;
    int lane = threadIdx.x & 63;
    int wslot = threadIdx.x >> 6;
    int slot = lane >> 4;
    int sub  = lane & 15;
    int dd   = sub * 4;

    if (hi > lo) {
        // ---------------- KG entity block ----------------
        for (int i = threadIdx.x; i < 16 * 16; i += blockDim.x)
            relS4[i] = ((const float4*)rel_emb)[i];
        __syncthreads();
        int wid = (int)lo * 4 + wslot;
        if (wid >= n_ent) return;
        int s = off_h[wid], e = off_h[wid + 1];
        uint3 qw = *(const uint3*)(pk12 + (size_t)wid * 192 + sub * 12);
        float q0 = bflo(qw.x), q1 = bfhi(qw.x), q2 = bflo(qw.y), q3 = bfhi(qw.y);
        float num0 = 0.f, num1 = 0.f, num2 = 0.f, num3 = 0.f, den = 0.f;
        int j = s;
        for (; j + 15 < e; j += 16) {         // 4 groups of 4 edges, all gathers in flight
            int pA = col_h[j + slot];
            int pB = col_h[j + 4 + slot];
            int pC = col_h[j + 8 + slot];
            int pD = col_h[j + 12 + slot];
            uint3 wA = *(const uint3*)(pk12 + (size_t)(pA & 131071) * 192 + sub * 12);
            uint3 wB = *(const uint3*)(pk12 + (size_t)(pB & 131071) * 192 + sub * 12);
            uint3 wC = *(const uint3*)(pk12 + (size_t)(pC & 131071) * 192 + sub * 12);
            uint3 wD = *(const uint3*)(pk12 + (size_t)(pD & 131071) * 192 + sub * 12);
            float4 rlA = relS4[(pA >> 17) * 16 + sub];
            float4 rlB = relS4[(pB >> 17) * 16 + sub];
            float4 rlC = relS4[(pC >> 17) * 16 + sub];
            float4 rlD = relS4[(pD >> 17) * 16 + sub];
            KG_EDGE12(wA, rlA, false);
            KG_EDGE12(wB, rlB, false);
            KG_EDGE12(wC, rlC, false);
            KG_EDGE12(wD, rlD, false);
        }
        for (; j + 7 < e; j += 8) {           // 2 groups
            int pA = col_h[j + slot];
            int pB = col_h[j + 4 + slot];
            uint3 wA = *(const uint3*)(pk12 + (size_t)(pA & 131071) * 192 + sub * 12);
            uint3 wB = *(const uint3*)(pk12 + (size_t)(pB & 131071) * 192 + sub * 12);
            float4 rlA = relS4[(pA >> 17) * 16 + sub];
            float4 rlB = relS4[(pB >> 17) * 16 + sub];
            KG_EDGE12(wA, rlA, false);
            KG_EDGE12(wB, rlB, false);
        }
        for (; j < e; j += 4) {               // remainder (may have dummy lanes)
            int jj = j + slot;
            bool invd = jj >= e;
            if (invd) jj = e - 1;
            int p = col_h[jj];
            uint3 w = *(const uint3*)(pk12 + (size_t)(p & 131071) * 192 + sub * 12);
            float4 rl = relS4[(p >> 17) * 16 + sub];
            KG_EDGE12(w, rl, invd);
        }
        den  += __shfl_xor(den, 16, 64);  den  += __shfl_xor(den, 32, 64);
        num0 += __shfl_xor(num0, 16, 64); num0 += __shfl_xor(num0, 32, 64);
        num1 += __shfl_xor(num1, 16, 64); num1 += __shfl_xor(num1, 32, 64);
        num2 += __shfl_xor(num2, 16, 64); num2 += __shfl_xor(num2, 32, 64);
        num3 += __shfl_xor(num3, 16, 64); num3 += __shfl_xor(num3, 32, 64);
        float dinv = (e > s) ? 1.f / den : 0.f;
        float v0 = num0 * dinv, v1 = num1 * dinv, v2 = num2 * dinv, v3 = num3 * dinv;
        float ss = fmaf(v0, v0, fmaf(v1, v1, fmaf(v2, v2, v3 * v3)));
        ss += __shfl_xor(ss, 1, 64);
        ss += __shfl_xor(ss, 2, 64);
        ss += __shfl_xor(ss, 4, 64);
        ss += __shfl_xor(ss, 8, 64);
        float rn = 1.f / fmaxf(sqrtf(ss), 1e-12f);
        float o0 = v0 * rn, o1 = v1 * rn, o2 = v2 * rn, o3 = v3 * rn;
        if (slot == 0) {
            size_t ix = (size_t)wid * EMB + dd;
            if (HOP1) {
                ushort4 nb; nb.x = f2bf(o0); nb.y = f2bf(o1); nb.z = f2bf(o2); nb.w = f2bf(o3);
                *(ushort4*)&enorm_out[ix] = nb;
                float4 bv = *(const float4*)&e_base[ix];
                *(float4*)&e_res[ix] = make_float4(bv.x + o0, bv.y + o1, bv.z + o2, bv.w + o3);
            } else {
                float4 rv = *(const float4*)&e_res[ix];
                *(float4*)&e_res[ix] = make_float4(rv.x + o0, rv.y + o1, rv.z + o2, rv.w + o3);
            }
        }
    } else if (HOP1) {
        // ---------------- UI user block (fp8 value table), hop-1 only ----------------
        int wid = (bid - (int)lo) * 4 + wslot;
        if (wid >= n_usr) return;
        int s = off_u[wid], e = off_u[wid + 1];
        float a0 = 0.f, a1 = 0.f, a2 = 0.f, a3 = 0.f;
        int j = s;
        for (; j + 7 < e; j += 8) {
            unsigned cA = col_ui[j + slot];
            unsigned cB = col_ui[j + 4 + slot];
            unsigned vA = vl[(size_t)(cA & 131071u) * 16 + sub];
            unsigned vB = vl[(size_t)(cB & 131071u) * 16 + sub];
            float wvA = (cA >> 17) * (1.f / 32767.f);
            float wvB = (cB >> 17) * (1.f / 32767.f);
            floatx2 lA = fp8lo(vA), hA = fp8hi(vA);
            a0 = fmaf(wvA, lA.x, a0); a1 = fmaf(wvA, lA.y, a1);
            a2 = fmaf(wvA, hA.x, a2); a3 = fmaf(wvA, hA.y, a3);
            floatx2 lB = fp8lo(vB), hB = fp8hi(vB);
            a0 = fmaf(wvB, lB.x, a0); a1 = fmaf(wvB, lB.y, a1);
            a2 = fmaf(wvB, hB.x, a2); a3 = fmaf(wvB, hB.y, a3);
        }
        for (; j < e; j += 4) {
            int jj = j + slot;
            bool invd = jj >= e;
            if (invd) jj = e - 1;
            unsigned c = col_ui[jj];
            float wv = invd ? 0.f : (c >> 17) * (1.f / 32767.f);
            unsigned vv = vl[(size_t)(c & 131071u) * 16 + sub];
            floatx2 vlo = fp8lo(vv), vhi = fp8hi(vv);
            a0 = fmaf(wv, vlo.x, a0);
            a1 = fmaf(wv, vlo.y, a1);
            a2 = fmaf(wv, vhi.x, a2);
            a3 = fmaf(wv, vhi.y, a3);
        }
        a0 += __shfl_xor(a0, 16, 64); a0 += __shfl_xor(a0, 32, 64);
        a1 += __shfl_xor(a1, 16, 64); a1 += __shfl_xor(a1, 32, 64);
        a2 += __shfl_xor(a2, 16, 64); a2 += __shfl_xor(a2, 32, 64);
        a3 += __shfl_xor(a3, 16, 64); a3 += __shfl_xor(a3, 32, 64);
        float ss = fmaf(a0, a0, fmaf(a1, a1, fmaf(a2, a2, a3 * a3)));
        ss += __shfl_xor(ss, 1, 64);
        ss += __shfl_xor(ss, 2, 64);
        ss += __shfl_xor(ss, 4, 64);
        ss += __shfl_xor(ss, 8, 64);
        float rn = 1.f / fmaxf(sqrtf(ss), 1e-12f);
        float o0 = a0 * rn, o1 = a1 * rn, o2 = a2 * rn, o3 = a3 * rn;
        if (slot == 0) {
            size_t ix = (size_t)wid * EMB + dd;
            float4 bv = *(const float4*)&u_base[ix];
            *(float4*)&u_res[ix] = make_float4(bv.x + o0, bv.y + o1, bv.z + o2, bv.w + o3);
        }
    }
}

// ---- P2: hop-2 proj (enorm -> pk12_2) MERGED with hop-2 UI agg (256 threads; 512 caused
// a VGPR-quantization occupancy cliff: 21.6% occ, 122 us in round 21) ----
__global__ void __launch_bounds__(256) p2_proj_ui(
        const unsigned short* __restrict__ enorm, const float* __restrict__ W,
        unsigned char* __restrict__ pk12_2, int n_ent,
        const int* __restrict__ off_u, const unsigned* __restrict__ col_ui,
        float* __restrict__ u_res, int n_usr) {
    __shared__ float sh[64 * 64];
    int b = blockIdx.x;
    int lane = threadIdx.x & 63;
    if (b < P2PROJ) {
        for (int i = threadIdx.x; i < 64 * 64; i += 256) sh[i] = W[i];
        __syncthreads();
        int g0 = b * 4 + (threadIdx.x >> 6);
        proj_rows12<true>(enorm, (const float4*)sh, pk12_2, nullptr, n_ent, g0, P2PROJ * 4, lane);
        return;
    }
    int wid = (b - P2PROJ) * 4 + (threadIdx.x >> 6);
    if (wid >= n_usr) return;
    int slot = lane >> 4;
    int sub  = lane & 15;
    int dd   = sub * 4;
    int s = off_u[wid], e = off_u[wid + 1];
    float a0 = 0.f, a1 = 0.f, a2 = 0.f, a3 = 0.f;
    int j = s;
    for (; j + 7 < e; j += 8) {
        unsigned cA = col_ui[j + slot];
        unsigned cB = col_ui[j + 4 + slot];
        ushort4 vA = *(const ushort4*)&enorm[(size_t)(cA & 131071u) * EMB + dd];
        ushort4 vB = *(const ushort4*)&enorm[(size_t)(cB & 131071u) * EMB + dd];
        float wvA = (cA >> 17) * (1.f / 32767.f);
        float wvB = (cB >> 17) * (1.f / 32767.f);
        a0 = fmaf(wvA, bf2f(vA.x), a0); a1 = fmaf(wvA, bf2f(vA.y), a1);
        a2 = fmaf(wvA, bf2f(vA.z), a2); a3 = fmaf(wvA, bf2f(vA.w), a3);
        a0 = fmaf(wvB, bf2f(vB.x), a0); a1 = fmaf(wvB, bf2f(vB.y), a1);
        a2 = fmaf(wvB, bf2f(vB.z), a2); a3 = fmaf(wvB, bf2f(vB.w), a3);
    }
    for (; j < e; j += 4) {
        int jj = j + slot;
        bool invd = jj >= e;
        if (invd) jj = e - 1;
        unsigned c = col_ui[jj];
        float wv = invd ? 0.f : (c >> 17) * (1.f / 32767.f);
        ushort4 v = *(const ushort4*)&enorm[(size_t)(c & 131071u) * EMB + dd];
        a0 = fmaf(wv, bf2f(v.x), a0);
        a1 = fmaf(wv, bf2f(v.y), a1);
        a2 = fmaf(wv, bf2f(v.z), a2);
        a3 = fmaf(wv, bf2f(v.w), a3);
    }
    a0 += __shfl_xor(a0, 16, 64); a0 += __shfl_xor(a0, 32, 64);
    a1 += __shfl_xor(a1, 16, 64); a1 += __shfl_xor(a1, 32, 64);
    a2 += __shfl_xor(a2, 16, 64); a2 += __shfl_xor(a2, 32, 64);
    a3 += __shfl_xor(a3, 16, 64); a3 += __shfl_xor(a3, 32, 64);
    float ss = fmaf(a0, a0, fmaf(a1, a1, fmaf(a2, a2, a3 * a3)));
    ss += __shfl_xor(ss, 1, 64);
    ss += __shfl_xor(ss, 2, 64);
    ss += __shfl_xor(ss, 4, 64);
    ss += __shfl_xor(ss, 8, 64);
    float rn = 1.f / fmaxf(sqrtf(ss), 1e-12f);
    if (slot == 0) {
        size_t ix = (size_t)wid * EMB + dd;
        float4 rv = *(const float4*)&u_res[ix];
        *(float4*)&u_res[ix] = make_float4(rv.x + a0 * rn, rv.y + a1 * rn,
                                           rv.z + a2 * rn, rv.w + a3 * rn);
    }
}

extern "C" void kernel_launch(void* const* d_in, const int* in_sizes, int n_in,
                              void* d_out, int out_size, void* d_ws, size_t ws_size,
                              hipStream_t stream) {
    const float* user_emb   = (const float*)d_in[0];
    const float* entity_emb = (const float*)d_in[1];
    const int*   edge_index = (const int*)d_in[2];   // [2, E]
    const int*   edge_type  = (const int*)d_in[3];   // [E]
    const int*   inter_edge = (const int*)d_in[4];   // [2, EI]
    const float* inter_w    = (const float*)d_in[5]; // [EI]
    const float* W_Q        = (const float*)d_in[6]; // [64,64]
    const float* rel_emb    = (const float*)d_in[7]; // [16,64]

    const int E     = in_sizes[3];
    const int EI    = in_sizes[5];
    const int n_ent = in_sizes[1] / EMB;
    const int n_usr = in_sizes[0] / EMB;

    const int* head = edge_index;
    const int* tail = edge_index + E;
    const int* iu   = inter_edge;
    const int* ii   = inter_edge + EI;

    const int nPartH = (n_ent + PRANGE - 1) >> PSHIFT;   // 196
    const int nPartU = (n_usr + PRANGE - 1) >> PSHIFT;   // 98

    // ---- workspace layout ----
    char* ws = (char*)d_ws;
    unsigned char* pk12   = (unsigned char*)ws;  ws += (size_t)n_ent * 192;   // hop-1 KG table
    unsigned*      vl     = (unsigned*)ws;       ws += (size_t)n_ent * 64;    // hop-1 UI fp8
    unsigned char* pk12_2 = (unsigned char*)ws;  ws += (size_t)n_ent * 192;   // hop-2 KG table
    unsigned short* enorm = (unsigned short*)ws; ws += (size_t)n_ent * EMB * 2;
    int*      col_h  = (int*)ws;               ws += (size_t)E * 4;
    unsigned* col_ui = (unsigned*)ws;          ws += (size_t)EI * 4;
    int*   off_h = (int*)ws;                   ws += (size_t)(n_ent + 1) * 4;
    int*   off_u = (int*)ws;                   ws += (size_t)(n_usr + 1) * 4;
    int*   pdK   = (int*)ws;                   ws += 256 * 4;
    int*   pdU   = (int*)ws;                   ws += 256 * 4;
    // buckets overlay pk12_2 + enorm (dead until agg1/p2 write them; k2 consumes first)
    unsigned* bktK = (unsigned*)pk12_2;                          // ~11.2 MB
    uint2v*   bktU = (uint2v*)(bktK + (size_t)nPartH * CAPK);    // ~11.2 MB

    float* e_res = (float*)d_out;
    float* u_res = e_res + (size_t)n_ent * EMB;

    // ---- CSR build: fixed-capacity bucket sort ----
    hipMemsetAsync(pdK, 0, 512 * 4, stream);
    k1_bucket_proj<<<NBK + NBU + P3_PROJ, 512, 0, stream>>>(
        head, tail, edge_type, E, pdK, bktK,
        iu, ii, inter_w, EI, pdU, bktU,
        entity_emb, W_Q, pk12, vl, n_ent, nPartH, nPartU);
    k2_sort<<<nPartH + nPartU, 512, 0, stream>>>(
        bktK, pdK, off_h, col_h, n_ent, nPartH, E,
        bktU, pdU, off_u, col_ui, n_usr, nPartU, EI);

    const int kgBlocks = (n_ent + 3) / 4;
    const int uiBlocks = (n_usr + 3) / 4;
    const int totalBlocks = kgBlocks + uiBlocks;

    // ---- hop 1 (KG+UI; emits enorm) ----
    agg_fused_kernel<true><<<totalBlocks, 256, 0, stream>>>(
        pk12, vl, enorm, rel_emb, off_h, col_h, off_u, col_ui,
        entity_emb, e_res, n_ent, user_emb, u_res, n_usr, kgBlocks, totalBlocks);

    // ---- hop-2 proj (enorm->pk12_2)  ||  hop-2 UI agg (enorm values) ----
    p2_proj_ui<<<P2PROJ + uiBlocks, 256, 0, stream>>>(
        enorm, W_Q, pk12_2, n_ent, off_u, col_ui, u_res, n_usr);

    // ---- hop 2 KG-only ----
    agg_fused_kernel<false><<<kgBlocks, 256, 0, stream>>>(
        pk12_2, nullptr, nullptr, rel_emb, off_h, col_h, nullptr, nullptr,
        nullptr, e_res, n_ent, nullptr, nullptr, 0, kgBlocks, kgBlocks);
}

// Round 23
// 386.017 us; speedup vs baseline: 1.1104x; 1.0483x over previous
//
#include <hip/hip_runtime.h>
#include <math.h>

#define EMB 64
static constexpr float INV_SQRT_DK = 0.17677669529663687f; // 1/sqrt(32)

#define NBK 128           // KG bucket blocks (long dense runs)
#define NBU 48            // UI bucket blocks
#define P3_PROJ 1024      // proj-role blocks in K1
#define P2PROJ 1024      // proj blocks in P2 (proj-only now)
#define PSHIFT 9          // 512-node partitions
#define PRANGE 512
#define CAPK 14336
#define CAPU 14336

typedef unsigned uint2v __attribute__((ext_vector_type(2)));
typedef float floatx2 __attribute__((ext_vector_type(2)));

__device__ inline unsigned short f2bf(float f) {
    union { float f; unsigned u; } v; v.f = f;
    unsigned r = v.u + 0x7FFF + ((v.u >> 16) & 1);   // round-to-nearest-even
    return (unsigned short)(r >> 16);
}
__device__ inline float bfhi(unsigned w) {           // high 16 bits as bf16
    union { float f; unsigned u; } v; v.u = w & 0xFFFF0000u; return v.f;
}
__device__ inline float bflo(unsigned w) {           // low 16 bits as bf16
    union { float f; unsigned u; } v; v.u = w << 16; return v.f;
}
__device__ inline float bf2f(unsigned short b) {
    union { float f; unsigned u; } v; v.u = ((unsigned)b) << 16; return v.f;
}
__device__ inline floatx2 fp8lo(unsigned v) {    // bytes 0,1 (e4m3)
    return __builtin_amdgcn_cvt_pk_f32_fp8((int)v, false);
}
__device__ inline floatx2 fp8hi(unsigned v) {    // bytes 2,3
    return __builtin_amdgcn_cvt_pk_f32_fp8((int)v, true);
}

// ---- proj core: wave handles 4 rows; lane=(rsub<<4)|sub handles dims 4sub..4sub+3.
// emits 12B/4dims: [bf16 pj0|pj1][bf16 pj2|pj3][4x fp8 val]; optionally vl (fp8 row).
template <bool FROM_BF16>
__device__ inline void proj_rows12(const void* __restrict__ ein, const float4* __restrict__ Wl4,
                                   unsigned char* __restrict__ pk12, unsigned* __restrict__ vl,
                                   int n, int g0, int nG, int lane) {
    int rsub = lane >> 4;
    int sub  = lane & 15;
    for (int g = g0; g * 4 < n; g += nG) {
        int r = g * 4 + rsub;
        float x0 = 0.f, x1 = 0.f, x2 = 0.f, x3 = 0.f;
        if (r < n) {
            if (FROM_BF16) {
                ushort4 xv = *(const ushort4*)((const unsigned short*)ein + (size_t)r * EMB + sub * 4);
                x0 = bf2f(xv.x); x1 = bf2f(xv.y); x2 = bf2f(xv.z); x3 = bf2f(xv.w);
            } else {
                float4 xv = *(const float4*)((const float*)ein + (size_t)r * EMB + sub * 4);
                x0 = xv.x; x1 = xv.y; x2 = xv.z; x3 = xv.w;
            }
        }
        float a0 = 0.f, a1 = 0.f, a2 = 0.f, a3 = 0.f;
#pragma unroll
        for (int kb = 0; kb < 16; ++kb) {
            int src = (rsub << 4) | kb;
            float e0 = __shfl(x0, src, 64);
            float e1 = __shfl(x1, src, 64);
            float e2 = __shfl(x2, src, 64);
            float e3 = __shfl(x3, src, 64);
            float4 w0 = Wl4[(kb * 4 + 0) * 16 + sub];
            float4 w1 = Wl4[(kb * 4 + 1) * 16 + sub];
            float4 w2 = Wl4[(kb * 4 + 2) * 16 + sub];
            float4 w3 = Wl4[(kb * 4 + 3) * 16 + sub];
            a0 = fmaf(e0, w0.x, a0); a1 = fmaf(e0, w0.y, a1); a2 = fmaf(e0, w0.z, a2); a3 = fmaf(e0, w0.w, a3);
            a0 = fmaf(e1, w1.x, a0); a1 = fmaf(e1, w1.y, a1); a2 = fmaf(e1, w1.z, a2); a3 = fmaf(e1, w1.w, a3);
            a0 = fmaf(e2, w2.x, a0); a1 = fmaf(e2, w2.y, a1); a2 = fmaf(e2, w2.z, a2); a3 = fmaf(e2, w2.w, a3);
            a0 = fmaf(e3, w3.x, a0); a1 = fmaf(e3, w3.y, a1); a2 = fmaf(e3, w3.z, a2); a3 = fmaf(e3, w3.w, a3);
        }
        if (r < n) {
            unsigned u0 = ((unsigned)f2bf(a1) << 16) | f2bf(a0);
            unsigned u1 = ((unsigned)f2bf(a3) << 16) | f2bf(a2);
            int p8 = __builtin_amdgcn_cvt_pk_fp8_f32(x0, x1, 0, false);
            p8 = __builtin_amdgcn_cvt_pk_fp8_f32(x2, x3, p8, true);
            uint3* dst = (uint3*)(pk12 + (size_t)r * 192 + sub * 12);
            *dst = make_uint3(u0, u1, (unsigned)p8);
            if (vl) vl[(size_t)r * 16 + sub] = (unsigned)p8;
        }
    }
}

// ---- K1: fixed-capacity partition bucketing MERGED with hop-1 proj (512 threads) ----
// Bucket stores are PLAIN (not nontemporal): L2 write-combines the dense runs.
__global__ void __launch_bounds__(512) k1_bucket_proj(
        const int* __restrict__ head, const int* __restrict__ tail,
        const int* __restrict__ etype, int E,
        int* __restrict__ pdK, unsigned* __restrict__ bktK,
        const int* __restrict__ iu, const int* __restrict__ ii,
        const float* __restrict__ w, int EI,
        int* __restrict__ pdU, uint2v* __restrict__ bktU,
        const float* __restrict__ e_in, const float* __restrict__ W,
        unsigned char* __restrict__ pk12, unsigned* __restrict__ vl,
        int n_ent, int nPartH, int nPartU) {
    __shared__ float sh[64 * 64];
    int b = blockIdx.x;
    int t = threadIdx.x;
    if (b >= NBK + NBU) {
        for (int i = t; i < 64 * 64; i += 512) sh[i] = W[i];
        __syncthreads();
        int lane = t & 63;
        int g0 = (b - (NBK + NBU)) * 8 + (t >> 6);
        proj_rows12<false>(e_in, (const float4*)sh, pk12, vl, n_ent, g0, P3_PROJ * 8, lane);
        return;
    }
    int* lc = (int*)sh;
    if (t < 256) lc[t] = 0;
    __syncthreads();
    if (b < NBK) {
        int chunk = (E + NBK - 1) / NBK;
        int lo = b * chunk, hi = min(lo + chunk, E);
        for (int e = lo + t; e < hi; e += 512)
            atomicAdd(&lc[__builtin_nontemporal_load(&head[e]) >> PSHIFT], 1);
        __syncthreads();
        if (t < nPartH)
            lc[t] = t * CAPK + atomicAdd(&pdK[t], lc[t]);
        __syncthreads();
        for (int e = lo + t; e < hi; e += 512) {
            int h = __builtin_nontemporal_load(&head[e]);
            int tl = __builtin_nontemporal_load(&tail[e]);
            int ty = __builtin_nontemporal_load(&etype[e]);
            int pos = atomicAdd(&lc[h >> PSHIFT], 1);
            bktK[pos] = ((unsigned)(h & (PRANGE - 1)) << 21) | (unsigned)(tl | ((ty - 1) << 17));
        }
    } else {
        int bb = b - NBK;
        int chunk = (EI + NBU - 1) / NBU;
        int lo = bb * chunk, hi = min(lo + chunk, EI);
        for (int e = lo + t; e < hi; e += 512)
            atomicAdd(&lc[__builtin_nontemporal_load(&iu[e]) >> PSHIFT], 1);
        __syncthreads();
        if (t < nPartU)
            lc[t] = t * CAPU + atomicAdd(&pdU[t], lc[t]);
        __syncthreads();
        for (int e = lo + t; e < hi; e += 512) {
            int u = __builtin_nontemporal_load(&iu[e]);
            int it = __builtin_nontemporal_load(&ii[e]);
            float wv = __builtin_nontemporal_load(&w[e]);
            int pos = atomicAdd(&lc[u >> PSHIFT], 1);
            unsigned wq = (unsigned)(wv * 32767.f + 0.5f);
            uint2v r; r.x = (unsigned)it | (wq << 17); r.y = (unsigned)u;
            bktU[pos] = r;
        }
    }
}

// ---- K2: per-partition LDS counting sort -> node-sorted col[] + off[] ----
__global__ void __launch_bounds__(512) k2_sort(
        const unsigned* __restrict__ bktK, const int* __restrict__ pdK,
        int* __restrict__ off_h, int* __restrict__ col_h, int n_ent, int nPartH, int E,
        const uint2v* __restrict__ bktU, const int* __restrict__ pdU,
        int* __restrict__ off_u, unsigned* __restrict__ col_ui, int n_usr, int nPartU, int EI) {
    __shared__ int hist[PRANGE];
    __shared__ int wsum[8];
    int t = threadIdx.x;
    int lane = t & 63, wv = t >> 6;
    int b = blockIdx.x;
    bool isU = b >= nPartH;
    int p = isU ? b - nPartH : b;
    const int* pd = isU ? pdU : pdK;
    int cnt = min(pd[p], isU ? CAPU : CAPK);
    int contrib = (t < p) ? pd[t] : 0;
#pragma unroll
    for (int m = 1; m <= 32; m <<= 1) contrib += __shfl_xor(contrib, m, 64);
    if (lane == 0) wsum[wv] = contrib;
    hist[t] = 0;
    __syncthreads();
    int Sp = wsum[0] + wsum[1] + wsum[2] + wsum[3] + wsum[4] + wsum[5] + wsum[6] + wsum[7];
    if (!isU) {
        const unsigned* bk = bktK + (size_t)p * CAPK;
        for (int i = t; i < cnt; i += 512)
            atomicAdd(&hist[__builtin_nontemporal_load(&bk[i]) >> 21], 1);
    } else {
        const uint2v* bu = bktU + (size_t)p * CAPU;
        int plo0 = p << PSHIFT;
        for (int i = t; i < cnt; i += 512) {
            uint2v r = __builtin_nontemporal_load(&bu[i]);
            atomicAdd(&hist[(int)r.y - plo0], 1);
        }
    }
    __syncthreads();
    int v0 = 0, v1 = 0, ps = 0, incl = 0;
    if (t < 256) { v0 = hist[2 * t]; v1 = hist[2 * t + 1]; ps = v0 + v1; incl = ps; }
#pragma unroll
    for (int d = 1; d <= 32; d <<= 1) { int x = __shfl_up(incl, d, 64); if (lane >= d) incl += x; }
    __syncthreads();
    if (t < 256 && lane == 63) wsum[wv] = incl;
    __syncthreads();
    int plo = p << PSHIFT;
    if (t < 256) {
        int woff = 0;
        for (int i = 0; i < wv; ++i) woff += wsum[i];
        int ex = incl - ps + woff;
        int nmax = isU ? n_usr : n_ent;
        int* off = isU ? off_u : off_h;
        if (plo + 2 * t < nmax)     off[plo + 2 * t]     = Sp + ex;
        if (plo + 2 * t + 1 < nmax) off[plo + 2 * t + 1] = Sp + ex + v0;
        hist[2 * t] = Sp + ex;
        hist[2 * t + 1] = Sp + ex + v0;
    }
    if (b == 0 && t == 0) off_h[n_ent] = E;
    if (b == nPartH && t == 0) off_u[n_usr] = EI;
    __syncthreads();
    if (!isU) {
        const unsigned* bk = bktK + (size_t)p * CAPK;
        for (int i = t; i < cnt; i += 512) {
            unsigned r = __builtin_nontemporal_load(&bk[i]);
            int pos = atomicAdd(&hist[r >> 21], 1);
            col_h[pos] = (int)(r & 0x1FFFFFu);
        }
    } else {
        const uint2v* bu = bktU + (size_t)p * CAPU;
        for (int i = t; i < cnt; i += 512) {
            uint2v r = __builtin_nontemporal_load(&bu[i]);
            int pos = atomicAdd(&hist[(int)r.y - plo], 1);
            col_ui[pos] = r.x;
        }
    }
}

// per-edge KG compute: score from bf16 pj, values from fp8; accumulates num/den
#define KG_EDGE12(W, RL, INVD) {                                            \
        float prod = q0 * RL.x * bflo(W.x);                                 \
        prod = fmaf(q1 * RL.y, bfhi(W.x), prod);                            \
        prod = fmaf(q2 * RL.z, bflo(W.y), prod);                            \
        prod = fmaf(q3 * RL.w, bfhi(W.y), prod);                            \
        prod += __shfl_xor(prod, 1, 64);                                    \
        prod += __shfl_xor(prod, 2, 64);                                    \
        prod += __shfl_xor(prod, 4, 64);                                    \
        float ex = __expf(prod * INV_SQRT_DK);                              \
        if (INVD) ex = 0.f;                                                 \
        den += ex;                                                          \
        floatx2 vlo = fp8lo(W.z), vhi = fp8hi(W.z);                         \
        num0 = fmaf(ex * RL.x, vlo.x, num0);                                \
        num1 = fmaf(ex * RL.y, vlo.y, num1);                                \
        num2 = fmaf(ex * RL.z, vhi.x, num2);                                \
        num3 = fmaf(ex * RL.w, vhi.y, num3); }

// ------- fused agg, 4 dims/lane 4 edges/wave, KG x4 unroll; UI in BOTH hops (fp8 tables) -------
template <bool HOP1>
__global__ void __launch_bounds__(256) agg_fused_kernel(
        const unsigned char* __restrict__ pk12,
        const unsigned* __restrict__ vl,          // UI value table (hop1: vl, hop2: vl2)
        unsigned short* __restrict__ enorm_out,   // HOP1 out (bf16 rows for proj2)
        unsigned*       __restrict__ vl2_out,     // HOP1 out (fp8 rows for hop2 UI)
        const float* __restrict__ rel_emb,
        const int* __restrict__ off_h, const int* __restrict__ col_h,
        const int* __restrict__ off_u, const unsigned* __restrict__ col_ui,
        const float* __restrict__ e_base, float* __restrict__ e_res, int n_ent,
        const float* __restrict__ u_base, float* __restrict__ u_res,
        int n_usr, int kgBlocks, int totalBlocks) {
    __shared__ float4 relS4[16 * 16];
    int bid = blockIdx.x;
    size_t lo = (size_t)bid * kgBlocks / totalBlocks;
    size_t hi = (size_t)(bid + 1) * kgBlocks / totalBlocks;
    int lane = threadIdx.x & 63;
    int wslot = threadIdx.x >> 6;
    int slot = lane >> 4;
    int sub  = lane & 15;
    int dd   = sub * 4;

    if (hi > lo) {
        // ---------------- KG entity block ----------------
        for (int i = threadIdx.x; i < 16 * 16; i += blockDim.x)
            relS4[i] = ((const float4*)rel_emb)[i];
        __syncthreads();
        int wid = (int)lo * 4 + wslot;
        if (wid >= n_ent) return;
        int s = off_h[wid], e = off_h[wid + 1];
        uint3 qw = *(const uint3*)(pk12 + (size_t)wid * 192 + sub * 12);
        float q0 = bflo(qw.x), q1 = bfhi(qw.x), q2 = bflo(qw.y), q3 = bfhi(qw.y);
        float num0 = 0.f, num1 = 0.f, num2 = 0.f, num3 = 0.f, den = 0.f;
        int j = s;
        for (; j + 15 < e; j += 16) {         // 4 groups of 4 edges, all gathers in flight
            int pA = col_h[j + slot];
            int pB = col_h[j + 4 + slot];
            int pC = col_h[j + 8 + slot];
            int pD = col_h[j + 12 + slot];
            uint3 wA = *(const uint3*)(pk12 + (size_t)(pA & 131071) * 192 + sub * 12);
            uint3 wB = *(const uint3*)(pk12 + (size_t)(pB & 131071) * 192 + sub * 12);
            uint3 wC = *(const uint3*)(pk12 + (size_t)(pC & 131071) * 192 + sub * 12);
            uint3 wD = *(const uint3*)(pk12 + (size_t)(pD & 131071) * 192 + sub * 12);
            float4 rlA = relS4[(pA >> 17) * 16 + sub];
            float4 rlB = relS4[(pB >> 17) * 16 + sub];
            float4 rlC = relS4[(pC >> 17) * 16 + sub];
            float4 rlD = relS4[(pD >> 17) * 16 + sub];
            KG_EDGE12(wA, rlA, false);
            KG_EDGE12(wB, rlB, false);
            KG_EDGE12(wC, rlC, false);
            KG_EDGE12(wD, rlD, false);
        }
        for (; j + 7 < e; j += 8) {           // 2 groups
            int pA = col_h[j + slot];
            int pB = col_h[j + 4 + slot];
            uint3 wA = *(const uint3*)(pk12 + (size_t)(pA & 131071) * 192 + sub * 12);
            uint3 wB = *(const uint3*)(pk12 + (size_t)(pB & 131071) * 192 + sub * 12);
            float4 rlA = relS4[(pA >> 17) * 16 + sub];
            float4 rlB = relS4[(pB >> 17) * 16 + sub];
            KG_EDGE12(wA, rlA, false);
            KG_EDGE12(wB, rlB, false);
        }
        for (; j < e; j += 4) {               // remainder (may have dummy lanes)
            int jj = j + slot;
            bool invd = jj >= e;
            if (invd) jj = e - 1;
            int p = col_h[jj];
            uint3 w = *(const uint3*)(pk12 + (size_t)(p & 131071) * 192 + sub * 12);
            float4 rl = relS4[(p >> 17) * 16 + sub];
            KG_EDGE12(w, rl, invd);
        }
        den  += __shfl_xor(den, 16, 64);  den  += __shfl_xor(den, 32, 64);
        num0 += __shfl_xor(num0, 16, 64); num0 += __shfl_xor(num0, 32, 64);
        num1 += __shfl_xor(num1, 16, 64); num1 += __shfl_xor(num1, 32, 64);
        num2 += __shfl_xor(num2, 16, 64); num2 += __shfl_xor(num2, 32, 64);
        num3 += __shfl_xor(num3, 16, 64); num3 += __shfl_xor(num3, 32, 64);
        float dinv = (e > s) ? 1.f / den : 0.f;
        float v0 = num0 * dinv, v1 = num1 * dinv, v2 = num2 * dinv, v3 = num3 * dinv;
        float ss = fmaf(v0, v0, fmaf(v1, v1, fmaf(v2, v2, v3 * v3)));
        ss += __shfl_xor(ss, 1, 64);
        ss += __shfl_xor(ss, 2, 64);
        ss += __shfl_xor(ss, 4, 64);
        ss += __shfl_xor(ss, 8, 64);
        float rn = 1.f / fmaxf(sqrtf(ss), 1e-12f);
        float o0 = v0 * rn, o1 = v1 * rn, o2 = v2 * rn, o3 = v3 * rn;
        if (slot == 0) {
            size_t ix = (size_t)wid * EMB + dd;
            if (HOP1) {
                ushort4 nb; nb.x = f2bf(o0); nb.y = f2bf(o1); nb.z = f2bf(o2); nb.w = f2bf(o3);
                *(ushort4*)&enorm_out[ix] = nb;
                int p8 = __builtin_amdgcn_cvt_pk_fp8_f32(o0, o1, 0, false);
                p8 = __builtin_amdgcn_cvt_pk_fp8_f32(o2, o3, p8, true);
                vl2_out[(size_t)wid * 16 + sub] = (unsigned)p8;
                float4 bv = *(const float4*)&e_base[ix];
                *(float4*)&e_res[ix] = make_float4(bv.x + o0, bv.y + o1, bv.z + o2, bv.w + o3);
            } else {
                float4 rv = *(const float4*)&e_res[ix];
                *(float4*)&e_res[ix] = make_float4(rv.x + o0, rv.y + o1, rv.z + o2, rv.w + o3);
            }
        }
    } else {
        // ---------------- UI user block (fp8 value table), both hops ----------------
        int wid = (bid - (int)lo) * 4 + wslot;
        if (wid >= n_usr) return;
        int s = off_u[wid], e = off_u[wid + 1];
        float a0 = 0.f, a1 = 0.f, a2 = 0.f, a3 = 0.f;
        int j = s;
        for (; j + 7 < e; j += 8) {
            unsigned cA = col_ui[j + slot];
            unsigned cB = col_ui[j + 4 + slot];
            unsigned vA = vl[(size_t)(cA & 131071u) * 16 + sub];
            unsigned vB = vl[(size_t)(cB & 131071u) * 16 + sub];
            float wvA = (cA >> 17) * (1.f / 32767.f);
            float wvB = (cB >> 17) * (1.f / 32767.f);
            floatx2 lA = fp8lo(vA), hA = fp8hi(vA);
            a0 = fmaf(wvA, lA.x, a0); a1 = fmaf(wvA, lA.y, a1);
            a2 = fmaf(wvA, hA.x, a2); a3 = fmaf(wvA, hA.y, a3);
            floatx2 lB = fp8lo(vB), hB = fp8hi(vB);
            a0 = fmaf(wvB, lB.x, a0); a1 = fmaf(wvB, lB.y, a1);
            a2 = fmaf(wvB, hB.x, a2); a3 = fmaf(wvB, hB.y, a3);
        }
        for (; j < e; j += 4) {
            int jj = j + slot;
            bool invd = jj >= e;
            if (invd) jj = e - 1;
            unsigned c = col_ui[jj];
            float wv = invd ? 0.f : (c >> 17) * (1.f / 32767.f);
            unsigned vv = vl[(size_t)(c & 131071u) * 16 + sub];
            floatx2 vlo = fp8lo(vv), vhi = fp8hi(vv);
            a0 = fmaf(wv, vlo.x, a0);
            a1 = fmaf(wv, vlo.y, a1);
            a2 = fmaf(wv, vhi.x, a2);
            a3 = fmaf(wv, vhi.y, a3);
        }
        a0 += __shfl_xor(a0, 16, 64); a0 += __shfl_xor(a0, 32, 64);
        a1 += __shfl_xor(a1, 16, 64); a1 += __shfl_xor(a1, 32, 64);
        a2 += __shfl_xor(a2, 16, 64); a2 += __shfl_xor(a2, 32, 64);
        a3 += __shfl_xor(a3, 16, 64); a3 += __shfl_xor(a3, 32, 64);
        float ss = fmaf(a0, a0, fmaf(a1, a1, fmaf(a2, a2, a3 * a3)));
        ss += __shfl_xor(ss, 1, 64);
        ss += __shfl_xor(ss, 2, 64);
        ss += __shfl_xor(ss, 4, 64);
        ss += __shfl_xor(ss, 8, 64);
        float rn = 1.f / fmaxf(sqrtf(ss), 1e-12f);
        float o0 = a0 * rn, o1 = a1 * rn, o2 = a2 * rn, o3 = a3 * rn;
        if (slot == 0) {
            size_t ix = (size_t)wid * EMB + dd;
            if (HOP1) {
                float4 bv = *(const float4*)&u_base[ix];
                *(float4*)&u_res[ix] = make_float4(bv.x + o0, bv.y + o1, bv.z + o2, bv.w + o3);
            } else {
                float4 rv = *(const float4*)&u_res[ix];
                *(float4*)&u_res[ix] = make_float4(rv.x + o0, rv.y + o1, rv.z + o2, rv.w + o3);
            }
        }
    }
}

// ---- P2: hop-2 proj only (enorm -> pk12_2); 256 threads (512 hit a VGPR occupancy cliff) ----
__global__ void __launch_bounds__(256) p2_proj(
        const unsigned short* __restrict__ enorm, const float* __restrict__ W,
        unsigned char* __restrict__ pk12_2, int n_ent) {
    __shared__ float sh[64 * 64];
    for (int i = threadIdx.x; i < 64 * 64; i += 256) sh[i] = W[i];
    __syncthreads();
    int lane = threadIdx.x & 63;
    int g0 = blockIdx.x * 4 + (threadIdx.x >> 6);
    proj_rows12<true>(enorm, (const float4*)sh, pk12_2, nullptr, n_ent, g0, P2PROJ * 4, lane);
}

extern "C" void kernel_launch(void* const* d_in, const int* in_sizes, int n_in,
                              void* d_out, int out_size, void* d_ws, size_t ws_size,
                              hipStream_t stream) {
    const float* user_emb   = (const float*)d_in[0];
    const float* entity_emb = (const float*)d_in[1];
    const int*   edge_index = (const int*)d_in[2];   // [2, E]
    const int*   edge_type  = (const int*)d_in[3];   // [E]
    const int*   inter_edge = (const int*)d_in[4];   // [2, EI]
    const float* inter_w    = (const float*)d_in[5]; // [EI]
    const float* W_Q        = (const float*)d_in[6]; // [64,64]
    const float* rel_emb    = (const float*)d_in[7]; // [16,64]

    const int E     = in_sizes[3];
    const int EI    = in_sizes[5];
    const int n_ent = in_sizes[1] / EMB;
    const int n_usr = in_sizes[0] / EMB;

    const int* head = edge_index;
    const int* tail = edge_index + E;
    const int* iu   = inter_edge;
    const int* ii   = inter_edge + EI;

    const int nPartH = (n_ent + PRANGE - 1) >> PSHIFT;   // 196
    const int nPartU = (n_usr + PRANGE - 1) >> PSHIFT;   // 98

    // ---- workspace layout ----
    char* ws = (char*)d_ws;
    unsigned char* pk12   = (unsigned char*)ws;  ws += (size_t)n_ent * 192;   // hop-1 KG table
    unsigned*      vl     = (unsigned*)ws;       ws += (size_t)n_ent * 64;    // hop-1 UI fp8
    unsigned*      vl2    = (unsigned*)ws;       ws += (size_t)n_ent * 64;    // hop-2 UI fp8
    unsigned char* pk12_2 = (unsigned char*)ws;  ws += (size_t)n_ent * 192;   // hop-2 KG table
    unsigned short* enorm = (unsigned short*)ws; ws += (size_t)n_ent * EMB * 2;
    int*      col_h  = (int*)ws;               ws += (size_t)E * 4;
    unsigned* col_ui = (unsigned*)ws;          ws += (size_t)EI * 4;
    int*   off_h = (int*)ws;                   ws += (size_t)(n_ent + 1) * 4;
    int*   off_u = (int*)ws;                   ws += (size_t)(n_usr + 1) * 4;
    int*   pdK   = (int*)ws;                   ws += 256 * 4;
    int*   pdU   = (int*)ws;                   ws += 256 * 4;
    // buckets overlay pk12_2 + enorm (dead until agg1/p2 write them; k2 consumes first)
    unsigned* bktK = (unsigned*)pk12_2;                          // ~11.2 MB
    uint2v*   bktU = (uint2v*)(bktK + (size_t)nPartH * CAPK);    // ~11.2 MB

    float* e_res = (float*)d_out;
    float* u_res = e_res + (size_t)n_ent * EMB;

    // ---- CSR build: fixed-capacity bucket sort ----
    hipMemsetAsync(pdK, 0, 512 * 4, stream);
    k1_bucket_proj<<<NBK + NBU + P3_PROJ, 512, 0, stream>>>(
        head, tail, edge_type, E, pdK, bktK,
        iu, ii, inter_w, EI, pdU, bktU,
        entity_emb, W_Q, pk12, vl, n_ent, nPartH, nPartU);
    k2_sort<<<nPartH + nPartU, 512, 0, stream>>>(
        bktK, pdK, off_h, col_h, n_ent, nPartH, E,
        bktU, pdU, off_u, col_ui, n_usr, nPartU, EI);

    const int kgBlocks = (n_ent + 3) / 4;
    const int uiBlocks = (n_usr + 3) / 4;
    const int totalBlocks = kgBlocks + uiBlocks;

    // ---- hop 1 (KG+UI; emits enorm + vl2) ----
    agg_fused_kernel<true><<<totalBlocks, 256, 0, stream>>>(
        pk12, vl, enorm, vl2, rel_emb, off_h, col_h, off_u, col_ui,
        entity_emb, e_res, n_ent, user_emb, u_res, n_usr, kgBlocks, totalBlocks);

    // ---- hop-2 proj (enorm -> pk12_2), proj-only ----
    p2_proj<<<P2PROJ, 256, 0, stream>>>(enorm, W_Q, pk12_2, n_ent);

    // ---- hop 2 (KG+UI, UI values = vl2) ----
    agg_fused_kernel<false><<<totalBlocks, 256, 0, stream>>>(
        pk12_2, vl2, nullptr, nullptr, rel_emb, off_h, col_h, off_u, col_ui,
        nullptr, e_res, n_ent, nullptr, u_res, n_usr, kgBlocks, totalBlocks);
}